// Round 2
// 109.143 us; speedup vs baseline: 1.0795x; 1.0795x over previous
//
#include <hip/hip_runtime.h>

// PrimalDualNetwork: 10-iter Chambolle-Pock ROF on 2048x2048 fp32.
// R10b = R10 resubmitted verbatim (previous round died on an MI355X
// container/infra failure with no compile or test diagnostic; source
// audit found no hang/OOB/resource hazard). Structure:
//  - R9 numerics (packed-fp16 xt plane, fp32 primal regs, cone guard,
//    demasked sw) retiled for exact machine fill:
//  - tile 64x64, NT=1024 (16 waves), NPASS=2. Grid 32x32 = 1024 blocks =
//    2 blocks/CU x 512 slots = exactly 2 uniform rounds -> no partial
//    tail round (R9's grid 32x43=1376 left a 352-block tail at ~1.4
//    blocks/CU; OccupancyPercent 33%, VALUBusy 52%).
//  - total cone work conserved: per-block work x1.326, blocks x0.744.
//  - per-thread register state SHRINKS (2 passes vs 3), so
//    launch_bounds(1024,8) (forces VGPR<=64 -> 8 waves/SIMD -> full
//    2048 thr/CU residency). Tripwire: WRITE_SIZE >> 16.4 MB = spills.
//  - LDS 33.2 KB/block; 2 blocks = 66 KB < 160 KB.
// All R9 numerics inherited unchanged: x (primal) fp32 in registers,
// xt fp16 plane, final primal stores fp32 directly to global.

namespace {
constexpr int M = 2048, N = 2048;
constexpr float SIGMA     = 1.0f / (7.0f * 0.01f);
constexpr float TAUIS     = 0.01f * (7.0f * 0.01f);  // tau/sigma
constexpr float LT        = 4.0f * 0.01f;
constexpr float INV_DEN   = 1.0f / (1.0f + 4.0f * 0.01f);
constexpr int TW = 64, TH = 64;     // output tile
constexpr int PC = 88;              // plane cols (12 + 64 + 12)
constexpr int PR = 84;              // plane rows (10 + 64 + 10)
constexpr int UPR = 22;             // h4 units per row == PC/4
constexpr int PROC = 83;            // rows 0..82 processed (83 read-only)
constexpr int NU = PROC * UPR;      // 1826
constexpr int NT = 1024;            // 16 waves
constexpr int NPASS = 2;            // 2*1024 >= NU (and >= PR*UPR=1848)
constexpr int GY = M / TH;          // 32  (exact: no partial tiles)
} // namespace

typedef _Float16 h4 __attribute__((ext_vector_type(4)));
typedef unsigned uint32;

__device__ inline h4 h4splat(float v) {
    _Float16 s = (_Float16)v;
    return (h4){s, s, s, s};
}
__device__ inline int imax(int a, int b) { return a > b ? a : b; }
__device__ inline uint32 abit(uint32 hi, uint32 lo) {
    return __builtin_amdgcn_alignbit(hi, lo, 16);
}
__device__ inline h4 clamp1(h4 v) {
    return __builtin_elementwise_min(
               __builtin_elementwise_max(v, h4splat(-1.f)), h4splat(1.f));
}

__global__ __launch_bounds__(NT, 8) void pd_fused(
    const float* __restrict__ img, float* __restrict__ out,
    const float* __restrict__ w1p, const float* __restrict__ w2p)
{
    __shared__ __align__(16) _Float16 sXT16[PR * PC];  // 14784 B (xt, fp16)
    __shared__ __align__(16) _Float16 sQV[PR * PC];    // 14784 B
    __shared__ __align__(16) _Float16 sQH3[1840];      //  3680 B (qH[3]/unit)

    const int tid  = threadIdx.x;
    const int lane = tid & 63;
    const int c0 = blockIdx.x * TW, r0 = blockIdx.y * TH;
    const int gr0 = r0 - 10, gc0 = c0 - 12;
    const float w1 = w1p[0], w2 = w2p[0];

    // cone deactivation threshold per pass (active iff rem >= d)
    int dth_[NPASS];
    #pragma unroll
    for (int p = 0; p < NPASS; ++p) {
        int u = tid + p * NT;
        int li = u / UPR, lc = (u - li * UPR) * 4;
        int d = imax(imax(9 - li, li - (TH + 9)), imax(8 - lc, lc - 75));
        d = imax(d, 0);
        if (u >= NU) d = 100;
        dth_[p] = d;
    }

    // ---- stage img -> sXT16 (fp16; 0 outside image) ----
    #pragma unroll
    for (int p = 0; p < NPASS; ++p) {
        int su = tid + p * NT;
        if (su < PR * UPR) {
            int li = su / UPR, uj = su - li * UPR;
            int gi = gr0 + li, gj = gc0 + uj * 4;
            float4 v = make_float4(0.f, 0.f, 0.f, 0.f);
            if ((unsigned)gi < (unsigned)M && (unsigned)gj <= (unsigned)(N - 4))
                v = *(const float4*)&img[(size_t)gi * N + gj];
            h4 h; h[0] = (_Float16)v.x; h[1] = (_Float16)v.y;
                  h[2] = (_Float16)v.z; h[3] = (_Float16)v.w;
            *(h4*)&sXT16[su * 4] = h;
        }
    }
    __syncthreads();

    // register state: x fp32 (precision-critical), rest packed fp16
    float xr[NPASS][4];
    h4 xt16[NPASS], xi16[NPASS], yh[NPASS], yv[NPASS],
       swh[NPASS], swv[NPASS], qH[NPASS];

    // ---- init (== dual(0)): masked sigma*w, y0, q0 ----
    #pragma unroll
    for (int p = 0; p < NPASS; ++p) {
        int u = tid + p * NT;
        if (u < NU) {
            int bF = u * 4;
            int li = u / UPR;
            int gi = gr0 + li, gjb = gc0 + (u - li * UPR) * 4;
            h4 c16 = *(const h4*)&sXT16[bF];
            uint32 rrp = *(const uint32*)&sXT16[bF + 4];
            h4 dn = *(const h4*)&sXT16[bF + PC];
            uint2 xu = __builtin_bit_cast(uint2, c16);
            h4 xsh = __builtin_bit_cast(h4,
                         make_uint2(abit(xu.y, xu.x), abit(rrp, xu.y)));
            bool rok = (unsigned)gi < (unsigned)M;
            bool vok = rok && (gi < M - 1);
            h4 qv;
            #pragma unroll
            for (int l = 0; l < 4; ++l) {
                int gj = gjb + l;
                bool cok = (unsigned)gj < (unsigned)N;
                bool hok = rok && cok && (gj < N - 1);
                bool vk  = vok && cok;
                float ghf = hok ? (float)xsh[l] - (float)c16[l] : 0.f;
                float gvf = vk  ? (float)dn[l]  - (float)c16[l] : 0.f;
                float wh = fmaf(w2, __expf(-fabsf(ghf)), w1);
                float wv = fmaf(w2, __expf(-fabsf(gvf)), w1);
                float y0h = fminf(fmaxf(ghf * fmaf(SIGMA, wh, 1.f), -1.f), 1.f);
                float y0v = fminf(fmaxf(gvf * fmaf(SIGMA, wv, 1.f), -1.f), 1.f);
                float sh = hok ? SIGMA * wh : 0.f;
                float sv = vk  ? SIGMA * wv : 0.f;
                yh[p][l]  = (_Float16)y0h;  yv[p][l]  = (_Float16)y0v;
                swh[p][l] = (_Float16)sh;   swv[p][l] = (_Float16)sv;
                qH[p][l]  = (_Float16)(sh * y0h);
                qv[l]     = (_Float16)(sv * y0v);
                xr[p][l]  = (float)c16[l];
            }
            xi16[p] = c16; xt16[p] = c16;
            *(h4*)&sQV[bF] = qv;
            sQH3[u] = qH[p][3];
        }
    }
    __syncthreads();

    // ---- dual(t>=1): fully packed; y = clamp(y + sw*grad16(xt)); q = sw*y
    auto dual = [&](int rem) {
        #pragma unroll
        for (int p = 0; p < NPASS; ++p) {
            uint2 xu = __builtin_bit_cast(uint2, xt16[p]);
            uint32 rrp = __shfl_down(xu.x, 1, 64);   // hoisted (exec-safe)
            if (rem >= dth_[p]) {
                int bF = (tid + p * NT) * 4;
                if (lane == 63) rrp = *(const uint32*)&sXT16[bF + 4];
                h4 dn = *(const h4*)&sXT16[bF + PC];
                h4 xsh = __builtin_bit_cast(h4,
                             make_uint2(abit(xu.y, xu.x), abit(rrp, xu.y)));
                h4 ghh = xsh - xt16[p];              // v_pk_sub_f16
                h4 gvh = dn  - xt16[p];
                h4 nh = clamp1(yh[p] + swh[p] * ghh);  // sw=0 masks borders
                h4 nv = clamp1(yv[p] + swv[p] * gvh);
                yh[p] = nh; yv[p] = nv;
                h4 qh = swh[p] * nh;                 // q = sigma*w*y
                h4 qv = swv[p] * nv;
                qH[p] = qh;
                *(h4*)&sQV[bF] = qv;
                sQH3[bF >> 2] = qh[3];
            }
        }
    };

    // ---- primal: x = (x + (tau/sigma)*div(q) + lt*img)/(1+lt);
    //      xt = 1.5x - 0.5xo. last: store fp32 to global, skip LDS. ----
    auto primal = [&](int rem, bool last) {
        #pragma unroll
        for (int p = 0; p < NPASS; ++p) {
            if (rem >= dth_[p]) {
                int u = tid + p * NT, bF = u * 4;
                int bu = (bF >= UPR * 4) ? bF - PC : bF;  // row-0 junk tolerated
                h4 qvu = *(const h4*)&sQV[bu];
                h4 qv  = *(const h4*)&sQV[bF];
                uint32 qhl = *(const unsigned short*)&sQH3[imax(u - 1, 0)];
                uint2 qu = __builtin_bit_cast(uint2, qH[p]);
                h4 qsh = __builtin_bit_cast(h4,
                             make_uint2(abit(qu.x, qhl << 16), abit(qu.y, qu.x)));
                h4 dvg = (qH[p] - qsh) + (qv - qvu);     // v_pk_sub/add_f16
                float xtv[4];
                #pragma unroll
                for (int l = 0; l < 4; ++l) {
                    float dv = (float)dvg[l];
                    float xo = xr[p][l];
                    float xn = (fmaf(TAUIS, dv, xo) + LT * (float)xi16[p][l]) * INV_DEN;
                    xr[p][l] = xn;
                    xtv[l] = fmaf(0.5f, xn - xo, xn);    // 1.5x - 0.5xo
                }
                if (!last) {
                    h4 nx; nx[0] = (_Float16)xtv[0]; nx[1] = (_Float16)xtv[1];
                           nx[2] = (_Float16)xtv[2]; nx[3] = (_Float16)xtv[3];
                    xt16[p] = nx;
                    *(h4*)&sXT16[bF] = nx;
                } else {
                    int li = u / UPR, uj = u - li * UPR;
                    int gi = gr0 + li;
                    if (li >= 10 && uj >= 3 && uj <= 18 && gi < M) {
                        *(float4*)&out[(size_t)gi * N + (gc0 + uj * 4)] =
                            make_float4(xtv[0], xtv[1], xtv[2], xtv[3]);
                    }
                }
            }
        }
    };

    primal(9, false);          // t=0 (dual(0) fused into init)
    __syncthreads();
    #pragma unroll 1
    for (int t = 1; t < 10; ++t) {
        int rem = 9 - t;
        dual(rem);
        __syncthreads();
        primal(rem, t == 9);
        __syncthreads();
    }
}

extern "C" void kernel_launch(void* const* d_in, const int* in_sizes, int n_in,
                              void* d_out, int out_size, void* d_ws, size_t ws_size,
                              hipStream_t stream)
{
    const float* img = (const float*)d_in[0];
    const float* w1  = (const float*)d_in[1];
    const float* w2  = (const float*)d_in[2];
    float* out = (float*)d_out;

    dim3 grid(N / TW, GY);   // 32 x 32 = 1024 blocks = 2/CU x 512 slots
    pd_fused<<<grid, NT, 0, stream>>>(img, out, w1, w2);
}

// Round 3
// 108.581 us; speedup vs baseline: 1.0850x; 1.0052x over previous
//
#include <hip/hip_runtime.h>

// PrimalDualNetwork: 10-iter Chambolle-Pock ROF on 2048x2048 fp32.
// R11 = R10 (tile 64x64, NT=1024, NPASS=2, grid 32x32 = exact 2
// blocks/CU x 2 rounds) with the spill fix:
//  - R10's __launch_bounds__(1024,8) squeezed VGPR to 32 -> scratch
//    spills (WRITE_SIZE 16.4->40.7 MB tripwire fired; FETCH +5 MB).
//    The 2nd-arg->VGPR-cap mapping is inconsistent across block sizes
//    (R9: B=512,arg=4 -> 48 VGPR ok; R10: B=1024,arg=8 -> 32 VGPR,
//    spills), so drop it entirely.
//  - Use explicit __attribute__((amdgpu_waves_per_eu(8))): LLVM
//    semantics = min 8 waves/EU -> VGPR cap 512/8 = 64. State needs
//    ~50 (2 passes x 16 regs + temps; R9 fit 3 passes in 48), so no
//    spill expected, and <=64 VGPR keeps 8 waves/SIMD = 32 waves/CU
//    = 2 blocks/CU residency.
//  - Tripwires: VGPR_Count > 64 => occupancy halves (1 blk/CU);
//    WRITE_SIZE >> 16.4 MB => spills persist, theory wrong.
// All R9/R10 numerics unchanged: x (primal) fp32 in registers, xt fp16
// plane, cone guard, demasked sw, final primal stores fp32 to global.

namespace {
constexpr int M = 2048, N = 2048;
constexpr float SIGMA     = 1.0f / (7.0f * 0.01f);
constexpr float TAUIS     = 0.01f * (7.0f * 0.01f);  // tau/sigma
constexpr float LT        = 4.0f * 0.01f;
constexpr float INV_DEN   = 1.0f / (1.0f + 4.0f * 0.01f);
constexpr int TW = 64, TH = 64;     // output tile
constexpr int PC = 88;              // plane cols (12 + 64 + 12)
constexpr int PR = 84;              // plane rows (10 + 64 + 10)
constexpr int UPR = 22;             // h4 units per row == PC/4
constexpr int PROC = 83;            // rows 0..82 processed (83 read-only)
constexpr int NU = PROC * UPR;      // 1826
constexpr int NT = 1024;            // 16 waves
constexpr int NPASS = 2;            // 2*1024 >= NU (and >= PR*UPR=1848)
constexpr int GY = M / TH;          // 32  (exact: no partial tiles)
} // namespace

typedef _Float16 h4 __attribute__((ext_vector_type(4)));
typedef unsigned uint32;

__device__ inline h4 h4splat(float v) {
    _Float16 s = (_Float16)v;
    return (h4){s, s, s, s};
}
__device__ inline int imax(int a, int b) { return a > b ? a : b; }
__device__ inline uint32 abit(uint32 hi, uint32 lo) {
    return __builtin_amdgcn_alignbit(hi, lo, 16);
}
__device__ inline h4 clamp1(h4 v) {
    return __builtin_elementwise_min(
               __builtin_elementwise_max(v, h4splat(-1.f)), h4splat(1.f));
}

__global__ __launch_bounds__(NT) __attribute__((amdgpu_waves_per_eu(8)))
void pd_fused(
    const float* __restrict__ img, float* __restrict__ out,
    const float* __restrict__ w1p, const float* __restrict__ w2p)
{
    __shared__ __align__(16) _Float16 sXT16[PR * PC];  // 14784 B (xt, fp16)
    __shared__ __align__(16) _Float16 sQV[PR * PC];    // 14784 B
    __shared__ __align__(16) _Float16 sQH3[1840];      //  3680 B (qH[3]/unit)

    const int tid  = threadIdx.x;
    const int lane = tid & 63;
    const int c0 = blockIdx.x * TW, r0 = blockIdx.y * TH;
    const int gr0 = r0 - 10, gc0 = c0 - 12;
    const float w1 = w1p[0], w2 = w2p[0];

    // cone deactivation threshold per pass (active iff rem >= d)
    int dth_[NPASS];
    #pragma unroll
    for (int p = 0; p < NPASS; ++p) {
        int u = tid + p * NT;
        int li = u / UPR, lc = (u - li * UPR) * 4;
        int d = imax(imax(9 - li, li - (TH + 9)), imax(8 - lc, lc - 75));
        d = imax(d, 0);
        if (u >= NU) d = 100;
        dth_[p] = d;
    }

    // ---- stage img -> sXT16 (fp16; 0 outside image) ----
    #pragma unroll
    for (int p = 0; p < NPASS; ++p) {
        int su = tid + p * NT;
        if (su < PR * UPR) {
            int li = su / UPR, uj = su - li * UPR;
            int gi = gr0 + li, gj = gc0 + uj * 4;
            float4 v = make_float4(0.f, 0.f, 0.f, 0.f);
            if ((unsigned)gi < (unsigned)M && (unsigned)gj <= (unsigned)(N - 4))
                v = *(const float4*)&img[(size_t)gi * N + gj];
            h4 h; h[0] = (_Float16)v.x; h[1] = (_Float16)v.y;
                  h[2] = (_Float16)v.z; h[3] = (_Float16)v.w;
            *(h4*)&sXT16[su * 4] = h;
        }
    }
    __syncthreads();

    // register state: x fp32 (precision-critical), rest packed fp16
    float xr[NPASS][4];
    h4 xt16[NPASS], xi16[NPASS], yh[NPASS], yv[NPASS],
       swh[NPASS], swv[NPASS], qH[NPASS];

    // ---- init (== dual(0)): masked sigma*w, y0, q0 ----
    #pragma unroll
    for (int p = 0; p < NPASS; ++p) {
        int u = tid + p * NT;
        if (u < NU) {
            int bF = u * 4;
            int li = u / UPR;
            int gi = gr0 + li, gjb = gc0 + (u - li * UPR) * 4;
            h4 c16 = *(const h4*)&sXT16[bF];
            uint32 rrp = *(const uint32*)&sXT16[bF + 4];
            h4 dn = *(const h4*)&sXT16[bF + PC];
            uint2 xu = __builtin_bit_cast(uint2, c16);
            h4 xsh = __builtin_bit_cast(h4,
                         make_uint2(abit(xu.y, xu.x), abit(rrp, xu.y)));
            bool rok = (unsigned)gi < (unsigned)M;
            bool vok = rok && (gi < M - 1);
            h4 qv;
            #pragma unroll
            for (int l = 0; l < 4; ++l) {
                int gj = gjb + l;
                bool cok = (unsigned)gj < (unsigned)N;
                bool hok = rok && cok && (gj < N - 1);
                bool vk  = vok && cok;
                float ghf = hok ? (float)xsh[l] - (float)c16[l] : 0.f;
                float gvf = vk  ? (float)dn[l]  - (float)c16[l] : 0.f;
                float wh = fmaf(w2, __expf(-fabsf(ghf)), w1);
                float wv = fmaf(w2, __expf(-fabsf(gvf)), w1);
                float y0h = fminf(fmaxf(ghf * fmaf(SIGMA, wh, 1.f), -1.f), 1.f);
                float y0v = fminf(fmaxf(gvf * fmaf(SIGMA, wv, 1.f), -1.f), 1.f);
                float sh = hok ? SIGMA * wh : 0.f;
                float sv = vk  ? SIGMA * wv : 0.f;
                yh[p][l]  = (_Float16)y0h;  yv[p][l]  = (_Float16)y0v;
                swh[p][l] = (_Float16)sh;   swv[p][l] = (_Float16)sv;
                qH[p][l]  = (_Float16)(sh * y0h);
                qv[l]     = (_Float16)(sv * y0v);
                xr[p][l]  = (float)c16[l];
            }
            xi16[p] = c16; xt16[p] = c16;
            *(h4*)&sQV[bF] = qv;
            sQH3[u] = qH[p][3];
        }
    }
    __syncthreads();

    // ---- dual(t>=1): fully packed; y = clamp(y + sw*grad16(xt)); q = sw*y
    auto dual = [&](int rem) {
        #pragma unroll
        for (int p = 0; p < NPASS; ++p) {
            uint2 xu = __builtin_bit_cast(uint2, xt16[p]);
            uint32 rrp = __shfl_down(xu.x, 1, 64);   // hoisted (exec-safe)
            if (rem >= dth_[p]) {
                int bF = (tid + p * NT) * 4;
                if (lane == 63) rrp = *(const uint32*)&sXT16[bF + 4];
                h4 dn = *(const h4*)&sXT16[bF + PC];
                h4 xsh = __builtin_bit_cast(h4,
                             make_uint2(abit(xu.y, xu.x), abit(rrp, xu.y)));
                h4 ghh = xsh - xt16[p];              // v_pk_sub_f16
                h4 gvh = dn  - xt16[p];
                h4 nh = clamp1(yh[p] + swh[p] * ghh);  // sw=0 masks borders
                h4 nv = clamp1(yv[p] + swv[p] * gvh);
                yh[p] = nh; yv[p] = nv;
                h4 qh = swh[p] * nh;                 // q = sigma*w*y
                h4 qv = swv[p] * nv;
                qH[p] = qh;
                *(h4*)&sQV[bF] = qv;
                sQH3[bF >> 2] = qh[3];
            }
        }
    };

    // ---- primal: x = (x + (tau/sigma)*div(q) + lt*img)/(1+lt);
    //      xt = 1.5x - 0.5xo. last: store fp32 to global, skip LDS. ----
    auto primal = [&](int rem, bool last) {
        #pragma unroll
        for (int p = 0; p < NPASS; ++p) {
            if (rem >= dth_[p]) {
                int u = tid + p * NT, bF = u * 4;
                int bu = (bF >= UPR * 4) ? bF - PC : bF;  // row-0 junk tolerated
                h4 qvu = *(const h4*)&sQV[bu];
                h4 qv  = *(const h4*)&sQV[bF];
                uint32 qhl = *(const unsigned short*)&sQH3[imax(u - 1, 0)];
                uint2 qu = __builtin_bit_cast(uint2, qH[p]);
                h4 qsh = __builtin_bit_cast(h4,
                             make_uint2(abit(qu.x, qhl << 16), abit(qu.y, qu.x)));
                h4 dvg = (qH[p] - qsh) + (qv - qvu);     // v_pk_sub/add_f16
                float xtv[4];
                #pragma unroll
                for (int l = 0; l < 4; ++l) {
                    float dv = (float)dvg[l];
                    float xo = xr[p][l];
                    float xn = (fmaf(TAUIS, dv, xo) + LT * (float)xi16[p][l]) * INV_DEN;
                    xr[p][l] = xn;
                    xtv[l] = fmaf(0.5f, xn - xo, xn);    // 1.5x - 0.5xo
                }
                if (!last) {
                    h4 nx; nx[0] = (_Float16)xtv[0]; nx[1] = (_Float16)xtv[1];
                           nx[2] = (_Float16)xtv[2]; nx[3] = (_Float16)xtv[3];
                    xt16[p] = nx;
                    *(h4*)&sXT16[bF] = nx;
                } else {
                    int li = u / UPR, uj = u - li * UPR;
                    int gi = gr0 + li;
                    if (li >= 10 && uj >= 3 && uj <= 18 && gi < M) {
                        *(float4*)&out[(size_t)gi * N + (gc0 + uj * 4)] =
                            make_float4(xtv[0], xtv[1], xtv[2], xtv[3]);
                    }
                }
            }
        }
    };

    primal(9, false);          // t=0 (dual(0) fused into init)
    __syncthreads();
    #pragma unroll 1
    for (int t = 1; t < 10; ++t) {
        int rem = 9 - t;
        dual(rem);
        __syncthreads();
        primal(rem, t == 9);
        __syncthreads();
    }
}

extern "C" void kernel_launch(void* const* d_in, const int* in_sizes, int n_in,
                              void* d_out, int out_size, void* d_ws, size_t ws_size,
                              hipStream_t stream)
{
    const float* img = (const float*)d_in[0];
    const float* w1  = (const float*)d_in[1];
    const float* w2  = (const float*)d_in[2];
    float* out = (float*)d_out;

    dim3 grid(N / TW, GY);   // 32 x 32 = 1024 blocks = 2/CU x 512 slots
    pd_fused<<<grid, NT, 0, stream>>>(img, out, w1, w2);
}